// Round 3
// baseline (135.074 us; speedup 1.0000x reference)
//
#include <hip/hip_runtime.h>
#include <math.h>

#define VOX_N    256
#define NLINKS   8
#define NSPH     8

// Opaque single-rounded f32 ops (inline asm, NON-volatile): pins the exact
// instruction/rounding but lets the scheduler reorder by data deps only —
// volatile would force program-order between ALL asm statements, which
// serialized the 8 gathers behind each iteration's pen/max chain in R8.
__device__ __forceinline__ float fmul_o(float a, float b) {
    float r;
    asm("v_mul_f32 %0, %1, %2" : "=v"(r) : "v"(a), "v"(b));
    return r;
}
__device__ __forceinline__ float fadd_o(float a, float b) {
    float r;
    asm("v_add_f32 %0, %1, %2" : "=v"(r) : "v"(a), "v"(b));
    return r;
}

// Non-temporal load: same bits, same rounding — ONLY a cache-policy hint
// (`nt` bit on the global_load). Rationale: the harness's poison fill
// writes exactly 256MiB (the Infinity Cache size) before every timed
// iteration, leaving L3 fully DIRTY. Every line we allocate then forces an
// eviction+writeback of a dirty line into our critical path (~256MB of
// forced writeback on top of our ~130MB of reads ≈ the observed 127µs).
// NT marks our lines evict-first / no-allocate so our streaming reads stop
// flushing the harness's dirty lines synchronously. R1 evidence for this
// theory: pre-warming L3 with a 67MB sequential prefetch bought ~nothing
// (the prefetch just paid the same eviction tax itself).
__device__ __forceinline__ float ld_nt(const float* __restrict__ p) {
    return __builtin_nontemporal_load(p);
}

// one thread per (b,h,l); 8 sphere gathers per thread; shfl-sum over l.
//
// NUMERICS CONTRACT (hard-won across R0-R8; verified absmax == 0.0):
//  - pts: plain f32 mul/add chain, DESCENDING j:
//      q = ((r2*c2 + r1*c1) + r0*c0) + p,  every op rounds once (no FMA).
//  - voxel: floor((q + 1.28f) * 100.0f) — RECIPROCAL-MULTIPLY, not divide
//    (f32(1/0.01f) == exactly 100.0f; true divide FAILS at absmax 0.1875).
//    f64 anywhere fails worse (0.4375). Comparison is bf16-quantized, only
//    voxel flips are visible — these two choices are the whole ballgame.
//  - tail: max (exact-assoc, any order), +(-0.01f), clip[0,0.5], *4
//    (exact), butterfly l-sum (== numpy n=8 pairwise tree), * weight.
__global__ __launch_bounds__(256) void voxel_cost_kernel(
    const float* __restrict__ pos,   // [B*H*L*3]
    const float* __restrict__ rot,   // [B*H*L*9]
    const float* __restrict__ cen,   // [L*S*3]
    const float* __restrict__ rad,   // [L*S]
    const float* __restrict__ sdf,   // [256^3]
    const float* __restrict__ wgt,   // [1]
    float* __restrict__ out,         // [B*H]
    int total)                       // B*H*L
{
    __shared__ float s_cen[NLINKS * NSPH * 3];
    __shared__ float s_rad[NLINKS * NSPH];

    const int t = threadIdx.x;
    if (t < NLINKS * NSPH * 3) s_cen[t] = cen[t];
    if (t < NLINKS * NSPH)     s_rad[t] = rad[t];
    __syncthreads();

    const int gid = blockIdx.x * 256 + t;
    if (gid >= total) return;
    const int l = gid & (NLINKS - 1);

    // per-thread rotation (row-major 3x3) and translation — single-use
    // streams, non-temporal (no reuse; don't evict dirty L3 lines for them)
    const size_t rbase = (size_t)gid * 9;
    const float r0 = ld_nt(rot + rbase + 0);
    const float r1 = ld_nt(rot + rbase + 1);
    const float r2 = ld_nt(rot + rbase + 2);
    const float r3 = ld_nt(rot + rbase + 3);
    const float r4 = ld_nt(rot + rbase + 4);
    const float r5 = ld_nt(rot + rbase + 5);
    const float r6 = ld_nt(rot + rbase + 6);
    const float r7 = ld_nt(rot + rbase + 7);
    const float r8 = ld_nt(rot + rbase + 8);
    const size_t pbase = (size_t)gid * 3;
    const float p0 = ld_nt(pos + pbase + 0);
    const float p1 = ld_nt(pos + pbase + 1);
    const float p2 = ld_nt(pos + pbase + 2);

    // Phase 1: compute all 24 voxel indices, issue all 8 independent
    // gathers (memory-level parallelism: one latency, not eight).
    float g[NSPH];
    #pragma unroll
    for (int s = 0; s < NSPH; ++s) {
        const int cs = (l * NSPH + s) * 3;
        const float c0 = s_cen[cs + 0];
        const float c1 = s_cen[cs + 1];
        const float c2 = s_cen[cs + 2];
        // DESCENDING-j plain chain: ((r2*c2 + r1*c1) + r0*c0) + p
        const float q0 = fadd_o(fadd_o(fadd_o(fmul_o(r2, c2), fmul_o(r1, c1)), fmul_o(r0, c0)), p0);
        const float q1 = fadd_o(fadd_o(fadd_o(fmul_o(r5, c2), fmul_o(r4, c1)), fmul_o(r3, c0)), p1);
        const float q2 = fadd_o(fadd_o(fadd_o(fmul_o(r8, c2), fmul_o(r7, c1)), fmul_o(r6, c0)), p2);
        // voxel index: floor((q + 1.28f) * 100.0f), clip to [0,255]
        const int ix = min(max((int)floorf(fmul_o(fadd_o(q0, 1.28f), 100.0f)), 0), VOX_N - 1);
        const int iy = min(max((int)floorf(fmul_o(fadd_o(q1, 1.28f), 100.0f)), 0), VOX_N - 1);
        const int iz = min(max((int)floorf(fmul_o(fadd_o(q2, 1.28f), 100.0f)), 0), VOX_N - 1);
        g[s] = ld_nt(sdf + ((((ix << 8) + iy) << 8) + iz));
    }

    // Phase 2: combine. pen = rad - g; max over spheres (exact-assoc).
    float m = -3.402823466e38f;
    #pragma unroll
    for (int s = 0; s < NSPH; ++s) {
        const float pen = fadd_o(s_rad[l * NSPH + s], -g[s]);
        m = fmaxf(m, pen);
    }

    // res + DIST_THRESHOLD, clip to [0, 0.5], / 0.25 (exact *4)
    float res = fadd_o(m, -0.01f);
    res = fminf(fmaxf(res, 0.0f), 0.5f) * 4.0f;

    // sum over l: 8 consecutive lanes share (b,h); butterfly tree equals
    // numpy n=8 pairwise sum ((a0+a1)+(a2+a3))+((a4+a5)+(a6+a7))
    res = fadd_o(res, __shfl_xor(res, 1, 64));
    res = fadd_o(res, __shfl_xor(res, 2, 64));
    res = fadd_o(res, __shfl_xor(res, 4, 64));

    if (l == 0) out[gid >> 3] = fmul_o(wgt[0], res);
}

extern "C" void kernel_launch(void* const* d_in, const int* in_sizes, int n_in,
                              void* d_out, int out_size, void* d_ws, size_t ws_size,
                              hipStream_t stream) {
    const float* pos = (const float*)d_in[0];  // link_pos_seq [B,H,L,3]
    const float* rot = (const float*)d_in[1];  // link_rot_seq [B,H,L,3,3]
    const float* cen = (const float*)d_in[2];  // sphere_centers [L,S,3]
    const float* rad = (const float*)d_in[3];  // sphere_radii [L,S]
    const float* sdf = (const float*)d_in[4];  // sdf_grid [256,256,256]
    const float* wgt = (const float*)d_in[5];  // weight scalar
    float* out = (float*)d_out;                // [B,H]

    const int total = in_sizes[0] / 3;         // B*H*L = 262144
    const int blocks = (total + 255) / 256;
    hipLaunchKernelGGL(voxel_cost_kernel, dim3(blocks), dim3(256), 0, stream,
                       pos, rot, cen, rad, sdf, wgt, out, total);
}